// Round 1
// baseline (3583.403 us; speedup 1.0000x reference)
//
#include <hip/hip_runtime.h>

#define SQRTD 11.313708498984761f

// ---------------------------------------------------------------- k_G
// G[h,e,o]  = sum_d Wsel_nb [h,d,e] * Wk_nb [h,d,o]   (2*256*64)
// G2[h,e,p] = sum_d Wsel_poi[h,d,e] * Wk_poi[h,d,p]   (2*256*32)
__global__ void k_G(const float* __restrict__ Wsel_nb, const float* __restrict__ Wk_nb,
                    const float* __restrict__ Wsel_poi, const float* __restrict__ Wk_poi,
                    float* __restrict__ G, float* __restrict__ G2) {
    int g = blockIdx.x * 256 + threadIdx.x;
    if (g < 32768) {
        int h = g >> 14, rem = g & 16383, e = rem >> 6, o = rem & 63;
        float s = 0.f;
        for (int d = 0; d < 128; d++)
            s += Wsel_nb[(h*128 + d)*256 + e] * Wk_nb[(h*128 + d)*64 + o];
        G[g] = s;
    } else if (g < 49152) {
        int q = g - 32768;
        int h = q >> 13, rem = q & 8191, e = rem >> 5, p = rem & 31;
        float s = 0.f;
        for (int d = 0; d < 128; d++)
            s += Wsel_poi[(h*128 + d)*256 + e] * Wk_poi[(h*128 + d)*32 + p];
        G2[q] = s;
    }
}

// ---------------------------------------------------------------- k_enc
// enc[row,j] = leaky_relu(b_enc[j] + sum_o obs[row, 448+o] * W_enc[j,o])
// block=128 threads (j within half), 32 rows/block, grid=1024
__global__ void k_enc(const float* __restrict__ obs, const float* __restrict__ W_enc,
                      const float* __restrict__ b_enc, float* __restrict__ enc) {
    __shared__ float self_lds[32 * 64];
    __shared__ float wt[64 * 128];   // transposed [o][j] for conflict-free reads
    int t = threadIdx.x;
    int rowbase = blockIdx.x * 32;   // row = a*4096+b
    for (int g = t; g < 2048; g += 128) {
        int r = g >> 6, o = g & 63;
        self_lds[g] = obs[(rowbase + r)*2560 + 448 + o];
    }
    for (int half = 0; half < 2; half++) {
        __syncthreads();
        for (int g = t; g < 8192; g += 128) {
            int jj = g >> 6, o = g & 63;
            wt[o*128 + jj] = W_enc[(half*128 + jj)*64 + o];
        }
        __syncthreads();
        float be = b_enc[half*128 + t];
        for (int r = 0; r < 32; r++) {
            float acc = be;
            const float* s = &self_lds[r*64];
            #pragma unroll
            for (int o = 0; o < 64; o++) acc += s[o] * wt[o*128 + t];
            acc = acc >= 0.f ? acc : 0.01f * acc;
            enc[(rowbase + r)*256 + half*128 + t] = acc;
        }
    }
}

// ---------------------------------------------------------------- k_stage1
// T[o] = sum_e enc[row,e]*G[h,e,o];  logit[n] = sum_o obs[row, n*64+o]*T[o] / sqrt(D)
// block=256 (4 groups x 64 lanes), 8 rows/group, grid = 16 ha * 128 tiles
__global__ void k_stage1(const float* __restrict__ obs, const float* __restrict__ enc,
                         const float* __restrict__ G, float* __restrict__ logit_raw,
                         double* __restrict__ part1) {
    __shared__ float Gh[8192];          // one e-half of G[h]: [e_local(128)][o(64)]
    __shared__ float enc_lds[4][128];
    __shared__ double dsum[4];
    int blk = blockIdx.x;
    int ha = blk >> 7, tile = blk & 127;
    int h = ha >> 3, a = ha & 7;
    int t = threadIdx.x, lane = t & 63, grp = t >> 6;
    int rowb = a*4096 + tile*32 + grp*8;
    float T[8];
    #pragma unroll
    for (int i = 0; i < 8; i++) T[i] = 0.f;
    for (int half = 0; half < 2; half++) {
        __syncthreads();
        for (int g = t; g < 8192; g += 256) Gh[g] = G[h*16384 + half*8192 + g];
        __syncthreads();
        #pragma unroll
        for (int it = 0; it < 8; it++) {
            enc_lds[grp][lane]      = enc[(rowb + it)*256 + half*128 + lane];
            enc_lds[grp][lane + 64] = enc[(rowb + it)*256 + half*128 + 64 + lane];
            __syncthreads();   // uniform (all groups run 8 its)
            float tacc = T[it];
            for (int e = 0; e < 128; e++)
                tacc += enc_lds[grp][e] * Gh[e*64 + lane];
            T[it] = tacc;
        }
    }
    double lsum = 0.0;
    #pragma unroll
    for (int it = 0; it < 8; it++) {
        int row = rowb + it;
        #pragma unroll
        for (int n = 0; n < 7; n++) {
            float v = obs[row*2560 + n*64 + lane] * T[it];
            #pragma unroll
            for (int mm = 32; mm >= 1; mm >>= 1) v += __shfl_xor(v, mm, 64);
            v = v / SQRTD;
            if (lane == 0) {
                logit_raw[(ha*4096 + tile*32 + grp*8 + it)*7 + n] = v;
                lsum += (double)v;
            }
        }
    }
    if (lane == 0) dsum[grp] = lsum;
    __syncthreads();
    if (t == 0) part1[ha*128 + tile] = dsum[0] + dsum[1] + dsum[2] + dsum[3];
}

// ---------------------------------------------------------------- k_meanred
// deterministic tree reduction of 128 block partials -> mean scalar per (h,a)
__global__ void k_meanred(const double* __restrict__ partials, float* __restrict__ mean_out,
                          int denomN) {
    __shared__ double sd[128];
    int ha = blockIdx.x, t = threadIdx.x;
    sd[t] = partials[ha*128 + t];
    __syncthreads();
    for (int s = 64; s >= 1; s >>= 1) {
        if (t < s) sd[t] += sd[t + s];
        __syncthreads();
    }
    if (t == 0) mean_out[ha] = (float)(sd[0] / (double)denomN);
}

// ---------------------------------------------------------------- k_nbvals
// w = softmax_n(logit/denom); V = leaky(nb@Wv^T + bv); nb_all[.., h*128+d] = sum_n w*V
// block=128 (d), Wv row held in 64 VGPRs, 32 rows/block, grid = 16*128
__global__ void k_nbvals(const float* __restrict__ obs, const float* __restrict__ Wv_nb,
                         const float* __restrict__ bv_nb, const float* __restrict__ logit_raw,
                         const float* __restrict__ mean1, float* __restrict__ nb_all) {
    __shared__ float nbrow[448];
    int blk = blockIdx.x;
    int ha = blk >> 7, tile = blk & 127;
    int h = ha >> 3, a = ha & 7;
    int t = threadIdx.x;   // d
    float wreg[64];
    #pragma unroll
    for (int o = 0; o < 64; o++) wreg[o] = Wv_nb[(h*128 + t)*64 + o];
    float bv = bv_nb[h*128 + t];
    float denom = mean1[ha] + 1e-9f;
    for (int r = 0; r < 32; r++) {
        int b = tile*32 + r;
        __syncthreads();
        for (int g = t; g < 448; g += 128) nbrow[g] = obs[(a*4096 + b)*2560 + g];
        __syncthreads();
        const float* lr = &logit_raw[(ha*4096 + b)*7];
        float L[7];
        float m = -3.4e38f;
        #pragma unroll
        for (int n = 0; n < 7; n++) { L[n] = lr[n] / denom; m = fmaxf(m, L[n]); }
        float w[7]; float s = 0.f;
        #pragma unroll
        for (int n = 0; n < 7; n++) { w[n] = expf(L[n] - m); s += w[n]; }
        #pragma unroll
        for (int n = 0; n < 7; n++) w[n] = w[n] / s;
        float acc = 0.f;
        #pragma unroll
        for (int n = 0; n < 7; n++) {
            float va = bv;
            #pragma unroll
            for (int o = 0; o < 64; o++) va += nbrow[n*64 + o] * wreg[o];
            va = va >= 0.f ? va : 0.01f * va;
            acc += w[n] * va;
        }
        nb_all[(a*4096 + b)*256 + h*128 + t] = acc;
    }
}

// ---------------------------------------------------------------- k_stage2
// Tp[p] = sum_e nb_all[row,e]*G2[h,e,p]; lp[c] = sum_p poi[c,b,p]*Tp[p] / sqrt(D)
// block=256 (8 groups x 32 lanes p), 4 rows/group, grid = 16*128
__global__ void k_stage2(const float* __restrict__ obs, const float* __restrict__ nb_all,
                         const float* __restrict__ G2, float* __restrict__ lp_raw,
                         double* __restrict__ part2) {
    __shared__ float G2h[8192];       // [e(256)][p(32)]
    __shared__ float rowe[8][256];
    __shared__ double dsum[8];
    int blk = blockIdx.x;
    int ha = blk >> 7, tile = blk & 127;
    int h = ha >> 3, a = ha & 7;
    int t = threadIdx.x, lane = t & 31, grp = t >> 5;
    for (int g = t; g < 8192; g += 256) G2h[g] = G2[h*8192 + g];
    __syncthreads();
    double lsum = 0.0;
    for (int rr = 0; rr < 4; rr++) {
        int b = tile*32 + grp*4 + rr;
        for (int g = lane; g < 256; g += 32) rowe[grp][g] = nb_all[(a*4096 + b)*256 + g];
        float tp = 0.f;
        for (int e = 0; e < 256; e++) tp += rowe[grp][e] * G2h[e*32 + lane];
        int pbase = b*2560 + 512;     // poi lives in agent-0 rows
        for (int c = 0; c < 64; c++) {
            float v = obs[pbase + c*32 + lane] * tp;
            #pragma unroll
            for (int mm = 16; mm >= 1; mm >>= 1) v += __shfl_xor(v, mm, 32);
            v = v / SQRTD;
            if (lane == 0) {
                lp_raw[(ha*4096 + b)*64 + c] = v;
                lsum += (double)v;
            }
        }
    }
    if (lane == 0) dsum[grp] = lsum;
    __syncthreads();
    if (t == 0) {
        double s = 0.0;
        for (int g = 0; g < 8; g++) s += dsum[g];
        part2[ha*128 + tile] = s;
    }
}

// ---------------------------------------------------------------- k_colmax_part
// per (ha, chunk of 512 b): softmax rows over c, track per-column (max w, min b)
// block=256 = 4 waves; lane c = t&63; grid = 16*8
__global__ void k_colmax_part(const float* __restrict__ lp_raw, const float* __restrict__ mean2,
                              float* __restrict__ colv_p, int* __restrict__ colb_p) {
    int blk = blockIdx.x;
    int ha = blk >> 3, chunk = blk & 7;
    int t = threadIdx.x, c = t & 63, wv = t >> 6;
    float denom = mean2[ha] + 1e-9f;
    float bestv = -1e30f; int bestb = 1 << 30;
    for (int k = 0; k < 128; k++) {
        int b = chunk*512 + wv + 4*k;
        float x = lp_raw[(ha*4096 + b)*64 + c] / denom;
        float m = x;
        #pragma unroll
        for (int mm = 32; mm >= 1; mm >>= 1) m = fmaxf(m, __shfl_xor(m, mm, 64));
        float e = expf(x - m);
        float s = e;
        #pragma unroll
        for (int mm = 32; mm >= 1; mm >>= 1) s += __shfl_xor(s, mm, 64);
        float w = e / s;
        if (w > bestv) { bestv = w; bestb = b; }   // strict > keeps earliest b
    }
    __shared__ float sv[4][64];
    __shared__ int   sb[4][64];
    sv[wv][c] = bestv; sb[wv][c] = bestb;
    __syncthreads();
    if (t < 64) {
        float v = sv[0][t]; int bb = sb[0][t];
        for (int j = 1; j < 4; j++) {
            float vj = sv[j][t]; int bj = sb[j][t];
            if (vj > v || (vj == v && bj < bb)) { v = vj; bb = bj; }
        }
        colv_p[(ha*8 + chunk)*64 + t] = v;
        colb_p[(ha*8 + chunk)*64 + t] = bb;
    }
}

// ---------------------------------------------------------------- k_colmerge
__global__ void k_colmerge(const float* __restrict__ colv_p, const int* __restrict__ colb_p,
                           float* __restrict__ colv, int* __restrict__ colb) {
    int ha = blockIdx.x, c = threadIdx.x;   // 64 threads
    float v = colv_p[(ha*8)*64 + c]; int bb = colb_p[(ha*8)*64 + c];
    for (int j = 1; j < 8; j++) {
        float vj = colv_p[(ha*8 + j)*64 + c]; int bj = colb_p[(ha*8 + j)*64 + c];
        if (vj > v || (vj == v && bj < bb)) { v = vj; bb = bj; }
    }
    colv[ha*64 + c] = v; colb[ha*64 + c] = bb;
}

// ---------------------------------------------------------------- k_scan
// 16-step sequential argmax scan; exact jnp.argmax-first-occurrence semantics:
// masked column c contributes (0.0, flat=c) == wm zeros' first occurrence at b=0.
__global__ void k_scan(const float* __restrict__ obs, const float* __restrict__ colv,
                       const int* __restrict__ colb, float* __restrict__ out) {
    __shared__ float cif[8];
    __shared__ float ifc[64];
    int t = threadIdx.x;
    if (t < 64) {
        int idx = (32*t + 2047) & 2047;          // (32c - 1) mod 2048
        ifc[t] = obs[512 + idx];                 // agent 0, batch 0 cargo features
    }
    __syncthreads();
    if (t == 0) {
        for (int i = 0; i < 16; i++) {
            float gv = -1e30f; int gflat = 1 << 30;
            for (int c = 0; c < 64; c++) {
                float v; int flat;
                if (ifc[c] == 1.0f) { v = 0.0f; flat = c; }
                else { v = colv[i*64 + c]; flat = colb[i*64 + c]*64 + c; }
                if (v > gv || (v == gv && flat < gflat)) { gv = v; gflat = flat; }
            }
            if (gflat < 64) ifc[gflat] = 1.0f;   // OOB scatter dropped, like JAX
            cif[i & 7] = (float)gflat;           // agent = i % 8; later steps overwrite
        }
    }
    __syncthreads();
    for (int a = 0; a < 8; a++)
        for (int k = t; k < 4096; k += 256)
            out[a*4096 + k] = cif[a];
}

// ---------------------------------------------------------------- launch
extern "C" void kernel_launch(void* const* d_in, const int* in_sizes, int n_in,
                              void* d_out, int out_size, void* d_ws, size_t ws_size,
                              hipStream_t stream) {
    const float* obs      = (const float*)d_in[0];
    const float* W_enc    = (const float*)d_in[1];
    const float* b_enc    = (const float*)d_in[2];
    const float* Wk_nb    = (const float*)d_in[3];
    const float* Wsel_nb  = (const float*)d_in[4];
    const float* Wv_nb    = (const float*)d_in[5];
    const float* bv_nb    = (const float*)d_in[6];
    const float* Wk_poi   = (const float*)d_in[7];
    const float* Wsel_poi = (const float*)d_in[8];
    // d_in[9] Wv_poi, d_in[10] bv_poi: unused by the reference output
    float* out = (float*)d_out;

    char* ws = (char*)d_ws;
    float*  enc       = (float*) (ws + 0);          // 33554432 B
    float*  nb_all    = (float*) (ws + 33554432);   // 33554432 B
    float*  lp_raw    = (float*) (ws + 67108864);   // 16777216 B
    float*  logit_raw = (float*) (ws + 83886080);   // 1835008 B
    float*  G         = (float*) (ws + 85721088);   // 131072 B
    float*  G2        = (float*) (ws + 85852160);   // 65536 B
    double* part1     = (double*)(ws + 85917696);   // 16384 B
    double* part2     = (double*)(ws + 85934080);   // 16384 B
    float*  mean1     = (float*) (ws + 85950464);   // 64 B
    float*  mean2     = (float*) (ws + 85950528);   // 64 B
    float*  colv_p    = (float*) (ws + 85950592);   // 32768 B
    int*    colb_p    = (int*)   (ws + 85983360);   // 32768 B
    float*  colv      = (float*) (ws + 86016128);   // 4096 B
    int*    colb      = (int*)   (ws + 86020224);   // 4096 B

    hipLaunchKernelGGL(k_G,           dim3(192),  dim3(256), 0, stream,
                       Wsel_nb, Wk_nb, Wsel_poi, Wk_poi, G, G2);
    hipLaunchKernelGGL(k_enc,         dim3(1024), dim3(128), 0, stream,
                       obs, W_enc, b_enc, enc);
    hipLaunchKernelGGL(k_stage1,      dim3(2048), dim3(256), 0, stream,
                       obs, enc, G, logit_raw, part1);
    hipLaunchKernelGGL(k_meanred,     dim3(16),   dim3(128), 0, stream,
                       part1, mean1, 28672);
    hipLaunchKernelGGL(k_nbvals,      dim3(2048), dim3(128), 0, stream,
                       obs, Wv_nb, bv_nb, logit_raw, mean1, nb_all);
    hipLaunchKernelGGL(k_stage2,      dim3(2048), dim3(256), 0, stream,
                       obs, nb_all, G2, lp_raw, part2);
    hipLaunchKernelGGL(k_meanred,     dim3(16),   dim3(128), 0, stream,
                       part2, mean2, 262144);
    hipLaunchKernelGGL(k_colmax_part, dim3(128),  dim3(256), 0, stream,
                       lp_raw, mean2, colv_p, colb_p);
    hipLaunchKernelGGL(k_colmerge,    dim3(16),   dim3(64),  0, stream,
                       colv_p, colb_p, colv, colb);
    hipLaunchKernelGGL(k_scan,        dim3(1),    dim3(256), 0, stream,
                       obs, colv, colb, out);
}

// Round 2
// 2727.535 us; speedup vs baseline: 1.3138x; 1.3138x over previous
//
#include <hip/hip_runtime.h>

#define SQRTD 11.313708498984761f

// ---------------------------------------------------------------- k_G
// G[h,e,o]  = sum_d Wsel_nb [h,d,e] * Wk_nb [h,d,o]   (2*256*64)
// G2[h,e,p] = sum_d Wsel_poi[h,d,e] * Wk_poi[h,d,p]   (2*256*32)
__global__ void k_G(const float* __restrict__ Wsel_nb, const float* __restrict__ Wk_nb,
                    const float* __restrict__ Wsel_poi, const float* __restrict__ Wk_poi,
                    float* __restrict__ G, float* __restrict__ G2) {
    int g = blockIdx.x * 256 + threadIdx.x;
    if (g < 32768) {
        int h = g >> 14, rem = g & 16383, e = rem >> 6, o = rem & 63;
        float s = 0.f;
        for (int d = 0; d < 128; d++)
            s += Wsel_nb[(h*128 + d)*256 + e] * Wk_nb[(h*128 + d)*64 + o];
        G[g] = s;
    } else if (g < 49152) {
        int q = g - 32768;
        int h = q >> 13, rem = q & 8191, e = rem >> 5, p = rem & 31;
        float s = 0.f;
        for (int d = 0; d < 128; d++)
            s += Wsel_poi[(h*128 + d)*256 + e] * Wk_poi[(h*128 + d)*32 + p];
        G2[q] = s;
    }
}

// ---------------------------------------------------------------- k_enc
// enc[row,j] = leaky_relu(b_enc[j] + sum_o obs[row, 448+o] * W_enc[j,o])
// block=128 threads (j within half), 32 rows/block, grid=1024
__global__ void k_enc(const float* __restrict__ obs, const float* __restrict__ W_enc,
                      const float* __restrict__ b_enc, float* __restrict__ enc) {
    __shared__ float self_lds[32 * 64];
    __shared__ float wt[64 * 128];   // transposed [o][j] for conflict-free reads
    int t = threadIdx.x;
    int rowbase = blockIdx.x * 32;   // row = a*4096+b
    for (int g = t; g < 2048; g += 128) {
        int r = g >> 6, o = g & 63;
        self_lds[g] = obs[(rowbase + r)*2560 + 448 + o];
    }
    for (int half = 0; half < 2; half++) {
        __syncthreads();
        for (int g = t; g < 8192; g += 128) {
            int jj = g >> 6, o = g & 63;
            wt[o*128 + jj] = W_enc[(half*128 + jj)*64 + o];
        }
        __syncthreads();
        float be = b_enc[half*128 + t];
        for (int r = 0; r < 32; r++) {
            float acc = be;
            const float* s = &self_lds[r*64];
            #pragma unroll
            for (int o = 0; o < 64; o++) acc += s[o] * wt[o*128 + t];
            acc = acc >= 0.f ? acc : 0.01f * acc;
            enc[(rowbase + r)*256 + half*128 + t] = acc;
        }
    }
}

// ---------------------------------------------------------------- k_stage1
// T[o] = sum_e enc[row,e]*G[h,e,o];  logit[n] = sum_o obs[row, n*64+o]*T[o] / sqrt(D)
// block=256 (4 groups x 64 lanes), 8 rows/group, grid = 16 ha * 128 tiles
__global__ void k_stage1(const float* __restrict__ obs, const float* __restrict__ enc,
                         const float* __restrict__ G, float* __restrict__ logit_raw,
                         double* __restrict__ part1) {
    __shared__ float Gh[8192];          // one e-half of G[h]: [e_local(128)][o(64)]
    __shared__ float enc_lds[4][128];
    __shared__ double dsum[4];
    int blk = blockIdx.x;
    int ha = blk >> 7, tile = blk & 127;
    int h = ha >> 3, a = ha & 7;
    int t = threadIdx.x, lane = t & 63, grp = t >> 6;
    int rowb = a*4096 + tile*32 + grp*8;
    float T[8];
    #pragma unroll
    for (int i = 0; i < 8; i++) T[i] = 0.f;
    for (int half = 0; half < 2; half++) {
        __syncthreads();
        for (int g = t; g < 8192; g += 256) Gh[g] = G[h*16384 + half*8192 + g];
        __syncthreads();
        #pragma unroll
        for (int it = 0; it < 8; it++) {
            enc_lds[grp][lane]      = enc[(rowb + it)*256 + half*128 + lane];
            enc_lds[grp][lane + 64] = enc[(rowb + it)*256 + half*128 + 64 + lane];
            __syncthreads();   // uniform (all groups run 8 its)
            float tacc = T[it];
            for (int e = 0; e < 128; e++)
                tacc += enc_lds[grp][e] * Gh[e*64 + lane];
            T[it] = tacc;
        }
    }
    double lsum = 0.0;
    #pragma unroll
    for (int it = 0; it < 8; it++) {
        int row = rowb + it;
        #pragma unroll
        for (int n = 0; n < 7; n++) {
            float v = obs[row*2560 + n*64 + lane] * T[it];
            #pragma unroll
            for (int mm = 32; mm >= 1; mm >>= 1) v += __shfl_xor(v, mm, 64);
            v = v / SQRTD;
            if (lane == 0) {
                logit_raw[(ha*4096 + tile*32 + grp*8 + it)*7 + n] = v;
                lsum += (double)v;
            }
        }
    }
    if (lane == 0) dsum[grp] = lsum;
    __syncthreads();
    if (t == 0) part1[ha*128 + tile] = dsum[0] + dsum[1] + dsum[2] + dsum[3];
}

// ---------------------------------------------------------------- k_meanred
// deterministic tree reduction of 128 block partials -> mean scalar per (h,a)
__global__ void k_meanred(const double* __restrict__ partials, float* __restrict__ mean_out,
                          int denomN) {
    __shared__ double sd[128];
    int ha = blockIdx.x, t = threadIdx.x;
    sd[t] = partials[ha*128 + t];
    __syncthreads();
    for (int s = 64; s >= 1; s >>= 1) {
        if (t < s) sd[t] += sd[t + s];
        __syncthreads();
    }
    if (t == 0) mean_out[ha] = (float)(sd[0] / (double)denomN);
}

// ---------------------------------------------------------------- k_nbvals
// w = softmax_n(logit/denom); V = leaky(nb@Wv^T + bv); nb_all[.., h*128+d] = sum_n w*V
// block=256 = (h,d); both heads share one obs staging. Wv row in 16 float4 VGPRs.
// __launch_bounds__(256,2): VGPR cap 256 so wv4 (64 regs) stays register-resident.
// grid = 8 a * 128 tiles
__global__ __launch_bounds__(256, 2) void k_nbvals(
        const float* __restrict__ obs, const float* __restrict__ Wv_nb,
        const float* __restrict__ bv_nb, const float* __restrict__ logit_raw,
        const float* __restrict__ mean1, float* __restrict__ nb_all) {
    __shared__ float4 nb4[8][112];    // 8 rows x 448 floats
    int blk = blockIdx.x;
    int a = blk >> 7, tile = blk & 127;
    int t = threadIdx.x;
    int h = t >> 7, d = t & 127;     // wave-uniform h (waves 0,1 -> h0; 2,3 -> h1)
    float4 wv4[16];
    const float4* wrow = (const float4*)(Wv_nb + (h*128 + d)*64);
    #pragma unroll
    for (int oq = 0; oq < 16; oq++) wv4[oq] = wrow[oq];
    float bv = bv_nb[h*128 + d];
    float denom = mean1[h*8 + a] + 1e-9f;
    const float4* obs4 = (const float4*)obs;
    for (int rs = 0; rs < 4; rs++) {
        int b0 = tile*32 + rs*8;
        __syncthreads();
        for (int g = t; g < 896; g += 256) {
            int rr = g / 112, el = g - rr*112;
            nb4[rr][el] = obs4[(size_t)(a*4096 + b0 + rr)*640 + el];
        }
        __syncthreads();
        for (int rr = 0; rr < 8; rr++) {
            int b = b0 + rr;
            const float* lr = logit_raw + ((size_t)((h*8 + a)*4096 + b))*7;
            float L[7], va[7];
            float m = -3.4e38f;
            #pragma unroll
            for (int n = 0; n < 7; n++) { L[n] = lr[n] / denom; m = fmaxf(m, L[n]); }
            float s = 0.f;
            #pragma unroll
            for (int n = 0; n < 7; n++) { L[n] = expf(L[n] - m); s += L[n]; }
            #pragma unroll
            for (int n = 0; n < 7; n++) {
                float4 acc4 = {0.f, 0.f, 0.f, 0.f};
                #pragma unroll
                for (int oq = 0; oq < 16; oq++) {
                    float4 nb = nb4[rr][n*16 + oq];   // LDS broadcast (conflict-free)
                    acc4.x = fmaf(nb.x, wv4[oq].x, acc4.x);
                    acc4.y = fmaf(nb.y, wv4[oq].y, acc4.y);
                    acc4.z = fmaf(nb.z, wv4[oq].z, acc4.z);
                    acc4.w = fmaf(nb.w, wv4[oq].w, acc4.w);
                }
                float v = bv + ((acc4.x + acc4.y) + (acc4.z + acc4.w));
                va[n] = v >= 0.f ? v : 0.01f * v;
            }
            float acc = 0.f;
            #pragma unroll
            for (int n = 0; n < 7; n++) acc += (L[n] / s) * va[n];
            nb_all[((size_t)(a*4096 + b))*256 + h*128 + d] = acc;
        }
    }
}

// ---------------------------------------------------------------- k_stage2
// Tp[p] = sum_e nb_all[row,e]*G2[h,e,p]; lp[c] = sum_p poi[c,b,p]*Tp[p] / sqrt(D)
// block=256 (8 groups x 32 lanes p), 4 rows/group, grid = 16*128
__global__ void k_stage2(const float* __restrict__ obs, const float* __restrict__ nb_all,
                         const float* __restrict__ G2, float* __restrict__ lp_raw,
                         double* __restrict__ part2) {
    __shared__ float G2h[8192];       // [e(256)][p(32)]
    __shared__ float rowe[8][256];
    __shared__ double dsum[8];
    int blk = blockIdx.x;
    int ha = blk >> 7, tile = blk & 127;
    int h = ha >> 3, a = ha & 7;
    int t = threadIdx.x, lane = t & 31, grp = t >> 5;
    for (int g = t; g < 8192; g += 256) G2h[g] = G2[h*8192 + g];
    __syncthreads();
    double lsum = 0.0;
    for (int rr = 0; rr < 4; rr++) {
        int b = tile*32 + grp*4 + rr;
        for (int g = lane; g < 256; g += 32) rowe[grp][g] = nb_all[(a*4096 + b)*256 + g];
        float tp = 0.f;
        for (int e = 0; e < 256; e++) tp += rowe[grp][e] * G2h[e*32 + lane];
        int pbase = b*2560 + 512;     // poi lives in agent-0 rows
        for (int c = 0; c < 64; c++) {
            float v = obs[pbase + c*32 + lane] * tp;
            #pragma unroll
            for (int mm = 16; mm >= 1; mm >>= 1) v += __shfl_xor(v, mm, 32);
            v = v / SQRTD;
            if (lane == 0) {
                lp_raw[(ha*4096 + b)*64 + c] = v;
                lsum += (double)v;
            }
        }
    }
    if (lane == 0) dsum[grp] = lsum;
    __syncthreads();
    if (t == 0) {
        double s = 0.0;
        for (int g = 0; g < 8; g++) s += dsum[g];
        part2[ha*128 + tile] = s;
    }
}

// ---------------------------------------------------------------- k_colmax_part
// per (ha, chunk of 256 b): softmax rows over c, track per-column (max w, min b)
// block=256 = 4 waves; lane c = t&63; grid = 16*16
__global__ void k_colmax_part(const float* __restrict__ lp_raw, const float* __restrict__ mean2,
                              float* __restrict__ colv_p, int* __restrict__ colb_p) {
    int blk = blockIdx.x;
    int ha = blk >> 4, chunk = blk & 15;
    int t = threadIdx.x, c = t & 63, wv = t >> 6;
    float denom = mean2[ha] + 1e-9f;
    float bestv = -1e30f; int bestb = 1 << 30;
    for (int k = 0; k < 64; k++) {
        int b = chunk*256 + wv + 4*k;
        float x = lp_raw[(ha*4096 + b)*64 + c] / denom;
        float m = x;
        #pragma unroll
        for (int mm = 32; mm >= 1; mm >>= 1) m = fmaxf(m, __shfl_xor(m, mm, 64));
        float e = expf(x - m);
        float s = e;
        #pragma unroll
        for (int mm = 32; mm >= 1; mm >>= 1) s += __shfl_xor(s, mm, 64);
        float w = e / s;
        if (w > bestv) { bestv = w; bestb = b; }   // strict > keeps earliest b per thread
    }
    __shared__ float sv[4][64];
    __shared__ int   sb[4][64];
    sv[wv][c] = bestv; sb[wv][c] = bestb;
    __syncthreads();
    if (t < 64) {
        float v = sv[0][t]; int bb = sb[0][t];
        for (int j = 1; j < 4; j++) {
            float vj = sv[j][t]; int bj = sb[j][t];
            if (vj > v || (vj == v && bj < bb)) { v = vj; bb = bj; }
        }
        colv_p[(ha*16 + chunk)*64 + t] = v;
        colb_p[(ha*16 + chunk)*64 + t] = bb;
    }
}

// ---------------------------------------------------------------- k_colmerge
__global__ void k_colmerge(const float* __restrict__ colv_p, const int* __restrict__ colb_p,
                           float* __restrict__ colv, int* __restrict__ colb) {
    int ha = blockIdx.x, c = threadIdx.x;   // 64 threads
    float v = colv_p[(ha*16)*64 + c]; int bb = colb_p[(ha*16)*64 + c];
    for (int j = 1; j < 16; j++) {
        float vj = colv_p[(ha*16 + j)*64 + c]; int bj = colb_p[(ha*16 + j)*64 + c];
        if (vj > v || (vj == v && bj < bb)) { v = vj; bb = bj; }
    }
    colv[ha*64 + c] = v; colb[ha*64 + c] = bb;
}

// ---------------------------------------------------------------- k_scan
// 16-step sequential argmax scan, parallel over 64 lanes (one column each).
// Exact jnp.argmax first-occurrence semantics: masked column c contributes
// (0.0, flat=c); winner tie-break is (v desc, flat asc) via butterfly.
__global__ void k_scan(const float* __restrict__ obs, const float* __restrict__ colv,
                       const int* __restrict__ colb, float* __restrict__ out) {
    __shared__ float cif_s[8];
    int t = threadIdx.x;
    if (t < 64) {
        int c = t;
        int idx = (32*c + 2047) & 2047;          // (32c - 1) mod 2048
        float ifc = obs[512 + idx];              // agent 0, batch 0 cargo features
        float cv[16]; int cb[16];
        #pragma unroll
        for (int i = 0; i < 16; i++) { cv[i] = colv[i*64 + c]; cb[i] = colb[i*64 + c]; }
        float cif[8];
        for (int i = 0; i < 16; i++) {
            float v; int flat;
            if (ifc == 1.0f) { v = 0.0f; flat = c; }
            else { v = cv[i]; flat = cb[i]*64 + c; }
            #pragma unroll
            for (int mm = 32; mm >= 1; mm >>= 1) {
                float vo = __shfl_xor(v, mm, 64);
                int fo = __shfl_xor(flat, mm, 64);
                if (vo > v || (vo == v && fo < flat)) { v = vo; flat = fo; }
            }
            if (flat < 64 && c == flat) ifc = 1.0f;  // OOB scatter dropped, like JAX
            cif[i & 7] = (float)flat;                // agent = i % 8; later steps overwrite
        }
        if (t == 0) {
            #pragma unroll
            for (int a = 0; a < 8; a++) cif_s[a] = cif[a];
        }
    }
    __syncthreads();
    for (int a = 0; a < 8; a++)
        for (int k = t; k < 4096; k += 256)
            out[a*4096 + k] = cif_s[a];
}

// ---------------------------------------------------------------- launch
extern "C" void kernel_launch(void* const* d_in, const int* in_sizes, int n_in,
                              void* d_out, int out_size, void* d_ws, size_t ws_size,
                              hipStream_t stream) {
    const float* obs      = (const float*)d_in[0];
    const float* W_enc    = (const float*)d_in[1];
    const float* b_enc    = (const float*)d_in[2];
    const float* Wk_nb    = (const float*)d_in[3];
    const float* Wsel_nb  = (const float*)d_in[4];
    const float* Wv_nb    = (const float*)d_in[5];
    const float* bv_nb    = (const float*)d_in[6];
    const float* Wk_poi   = (const float*)d_in[7];
    const float* Wsel_poi = (const float*)d_in[8];
    // d_in[9] Wv_poi, d_in[10] bv_poi: unused by the reference output
    float* out = (float*)d_out;

    char* ws = (char*)d_ws;
    float*  enc       = (float*) (ws + 0);          // 33554432 B
    float*  nb_all    = (float*) (ws + 33554432);   // 33554432 B
    float*  lp_raw    = (float*) (ws + 67108864);   // 16777216 B
    float*  logit_raw = (float*) (ws + 83886080);   // 1835008 B
    float*  G         = (float*) (ws + 85721088);   // 131072 B
    float*  G2        = (float*) (ws + 85852160);   // 65536 B
    double* part1     = (double*)(ws + 85917696);   // 16384 B
    double* part2     = (double*)(ws + 85934080);   // 16384 B
    float*  mean1     = (float*) (ws + 85950464);   // 64 B
    float*  mean2     = (float*) (ws + 85950528);   // 64 B
    float*  colv_p    = (float*) (ws + 85950592);   // 65536 B
    int*    colb_p    = (int*)   (ws + 86016128);   // 65536 B
    float*  colv      = (float*) (ws + 86081664);   // 4096 B
    int*    colb      = (int*)   (ws + 86085760);   // 4096 B

    hipLaunchKernelGGL(k_G,           dim3(192),  dim3(256), 0, stream,
                       Wsel_nb, Wk_nb, Wsel_poi, Wk_poi, G, G2);
    hipLaunchKernelGGL(k_enc,         dim3(1024), dim3(128), 0, stream,
                       obs, W_enc, b_enc, enc);
    hipLaunchKernelGGL(k_stage1,      dim3(2048), dim3(256), 0, stream,
                       obs, enc, G, logit_raw, part1);
    hipLaunchKernelGGL(k_meanred,     dim3(16),   dim3(128), 0, stream,
                       part1, mean1, 28672);
    hipLaunchKernelGGL(k_nbvals,      dim3(1024), dim3(256), 0, stream,
                       obs, Wv_nb, bv_nb, logit_raw, mean1, nb_all);
    hipLaunchKernelGGL(k_stage2,      dim3(2048), dim3(256), 0, stream,
                       obs, nb_all, G2, lp_raw, part2);
    hipLaunchKernelGGL(k_meanred,     dim3(16),   dim3(128), 0, stream,
                       part2, mean2, 262144);
    hipLaunchKernelGGL(k_colmax_part, dim3(256),  dim3(256), 0, stream,
                       lp_raw, mean2, colv_p, colb_p);
    hipLaunchKernelGGL(k_colmerge,    dim3(16),   dim3(64),  0, stream,
                       colv_p, colb_p, colv, colb);
    hipLaunchKernelGGL(k_scan,        dim3(1),    dim3(256), 0, stream,
                       obs, colv, colb, out);
}

// Round 3
// 1997.475 us; speedup vs baseline: 1.7940x; 1.3655x over previous
//
#include <hip/hip_runtime.h>

#define SQRTD 11.313708498984761f

// ---------------------------------------------------------------- k_G
// G[h,e,o]  = sum_d Wsel_nb [h,d,e] * Wk_nb [h,d,o]   (2*256*64)
// G2[h,e,p] = sum_d Wsel_poi[h,d,e] * Wk_poi[h,d,p]   (2*256*32)
__global__ void k_G(const float* __restrict__ Wsel_nb, const float* __restrict__ Wk_nb,
                    const float* __restrict__ Wsel_poi, const float* __restrict__ Wk_poi,
                    float* __restrict__ G, float* __restrict__ G2) {
    int g = blockIdx.x * 256 + threadIdx.x;
    if (g < 32768) {
        int h = g >> 14, rem = g & 16383, e = rem >> 6, o = rem & 63;
        float s = 0.f;
        for (int d = 0; d < 128; d++)
            s += Wsel_nb[(h*128 + d)*256 + e] * Wk_nb[(h*128 + d)*64 + o];
        G[g] = s;
    } else if (g < 49152) {
        int q = g - 32768;
        int h = q >> 13, rem = q & 8191, e = rem >> 5, p = rem & 31;
        float s = 0.f;
        for (int d = 0; d < 128; d++)
            s += Wsel_poi[(h*128 + d)*256 + e] * Wk_poi[(h*128 + d)*32 + p];
        G2[q] = s;
    }
}

// ---------------------------------------------------------------- k_enc
// enc[row,j] = leaky_relu(b_enc[j] + sum_o obs[row, 448+o] * W_enc[j,o])
// block=128 threads (j within half), 32 rows/block, grid=1024
__global__ void k_enc(const float* __restrict__ obs, const float* __restrict__ W_enc,
                      const float* __restrict__ b_enc, float* __restrict__ enc) {
    __shared__ float self_lds[32 * 64];
    __shared__ float wt[64 * 128];   // transposed [o][j] for conflict-free reads
    int t = threadIdx.x;
    int rowbase = blockIdx.x * 32;   // row = a*4096+b
    for (int g = t; g < 2048; g += 128) {
        int r = g >> 6, o = g & 63;
        self_lds[g] = obs[(rowbase + r)*2560 + 448 + o];
    }
    for (int half = 0; half < 2; half++) {
        __syncthreads();
        for (int g = t; g < 8192; g += 128) {
            int jj = g >> 6, o = g & 63;
            wt[o*128 + jj] = W_enc[(half*128 + jj)*64 + o];
        }
        __syncthreads();
        float be = b_enc[half*128 + t];
        for (int r = 0; r < 32; r++) {
            float acc = be;
            const float* s = &self_lds[r*64];
            #pragma unroll
            for (int o = 0; o < 64; o++) acc += s[o] * wt[o*128 + t];
            acc = acc >= 0.f ? acc : 0.01f * acc;
            enc[(rowbase + r)*256 + half*128 + t] = acc;
        }
    }
}

// ---------------------------------------------------------------- k_stage1
// T[row,o] = sum_e enc[row,e]*G[h,e,o]; logit[n] = dot(obs_nb[row,n,:], T)/sqrt(D)
// Wave w holds G[h, w*64+j, lane] in 64 VGPRs; enc comes in via wave-uniform
// scalar loads (readfirstlane'd base -> s_load + fma-with-SGPR). No LDS in
// the inner loop; cross-wave e-chunk partials combine through T_s.
// block=256 (4 waves), 32 rows/block, grid = 16 ha * 128 tiles
__global__ __launch_bounds__(256, 2) void k_stage1(
        const float* __restrict__ obs, const float* __restrict__ enc,
        const float* __restrict__ G, float* __restrict__ logit_raw,
        double* __restrict__ part1) {
    __shared__ float T_s[4][32][64];     // 32 KB
    __shared__ double dsum[4];
    int blk = blockIdx.x;
    int ha = blk >> 7, tile = blk & 127;
    int h = ha >> 3, a = ha & 7;
    int t = threadIdx.x, lane = t & 63;
    int wu = __builtin_amdgcn_readfirstlane(t >> 6);   // wave id, provably uniform
    int rowb = a*4096 + tile*32;

    // G chunk for this wave: e = wu*64 + j, o = lane
    float Greg[64];
    const float* gbase = G + h*16384 + wu*64*64 + lane;
    #pragma unroll
    for (int j = 0; j < 64; j++) Greg[j] = gbase[j*64];

    // phase 1: partial T over this wave's e-chunk, all 32 rows
    for (int r = 0; r < 32; r++) {
        const float* er = enc + (size_t)(rowb + r)*256 + wu*64;   // uniform base
        float acc = 0.f;
        #pragma unroll
        for (int q = 0; q < 16; q++) {
            float4 e4 = *(const float4*)(er + 4*q);   // s_load_dwordx4 expected
            acc = fmaf(e4.x, Greg[4*q+0], acc);
            acc = fmaf(e4.y, Greg[4*q+1], acc);
            acc = fmaf(e4.z, Greg[4*q+2], acc);
            acc = fmaf(e4.w, Greg[4*q+3], acc);
        }
        T_s[wu][r][lane] = acc;
    }
    __syncthreads();

    // phase 2: each wave finishes 8 rows: combine partials + logits
    double lsum = 0.0;
    for (int rr = 0; rr < 8; rr++) {
        int r = wu*8 + rr;
        int row = rowb + r;
        float T = (T_s[0][r][lane] + T_s[1][r][lane])
                + (T_s[2][r][lane] + T_s[3][r][lane]);
        #pragma unroll
        for (int n = 0; n < 7; n++) {
            float v = obs[(size_t)row*2560 + n*64 + lane] * T;
            #pragma unroll
            for (int mm = 32; mm >= 1; mm >>= 1) v += __shfl_xor(v, mm, 64);
            v = v / SQRTD;
            if (lane == 0) {
                logit_raw[(size_t)(ha*4096 + tile*32 + r)*7 + n] = v;
                lsum += (double)v;
            }
        }
    }
    if (lane == 0) dsum[wu] = lsum;
    __syncthreads();
    if (t == 0) part1[ha*128 + tile] = (dsum[0] + dsum[1]) + (dsum[2] + dsum[3]);
}

// ---------------------------------------------------------------- k_meanred
// deterministic tree reduction of 128 block partials -> mean scalar per (h,a)
__global__ void k_meanred(const double* __restrict__ partials, float* __restrict__ mean_out,
                          int denomN) {
    __shared__ double sd[128];
    int ha = blockIdx.x, t = threadIdx.x;
    sd[t] = partials[ha*128 + t];
    __syncthreads();
    for (int s = 64; s >= 1; s >>= 1) {
        if (t < s) sd[t] += sd[t + s];
        __syncthreads();
    }
    if (t == 0) mean_out[ha] = (float)(sd[0] / (double)denomN);
}

// ---------------------------------------------------------------- k_nbvals
// w = softmax_n(logit/denom); V = leaky(nb@Wv^T + bv); nb_all[.., h*128+d] = sum_n w*V
// block=256 = (h,d); both heads share one obs staging. Wv row in 16 float4 VGPRs.
__global__ __launch_bounds__(256, 2) void k_nbvals(
        const float* __restrict__ obs, const float* __restrict__ Wv_nb,
        const float* __restrict__ bv_nb, const float* __restrict__ logit_raw,
        const float* __restrict__ mean1, float* __restrict__ nb_all) {
    __shared__ float4 nb4[8][112];    // 8 rows x 448 floats
    int blk = blockIdx.x;
    int a = blk >> 7, tile = blk & 127;
    int t = threadIdx.x;
    int h = t >> 7, d = t & 127;     // wave-uniform h (waves 0,1 -> h0; 2,3 -> h1)
    float4 wv4[16];
    const float4* wrow = (const float4*)(Wv_nb + (h*128 + d)*64);
    #pragma unroll
    for (int oq = 0; oq < 16; oq++) wv4[oq] = wrow[oq];
    float bv = bv_nb[h*128 + d];
    float denom = mean1[h*8 + a] + 1e-9f;
    const float4* obs4 = (const float4*)obs;
    for (int rs = 0; rs < 4; rs++) {
        int b0 = tile*32 + rs*8;
        __syncthreads();
        for (int g = t; g < 896; g += 256) {
            int rr = g / 112, el = g - rr*112;
            nb4[rr][el] = obs4[(size_t)(a*4096 + b0 + rr)*640 + el];
        }
        __syncthreads();
        for (int rr = 0; rr < 8; rr++) {
            int b = b0 + rr;
            const float* lr = logit_raw + ((size_t)((h*8 + a)*4096 + b))*7;
            float L[7], va[7];
            float m = -3.4e38f;
            #pragma unroll
            for (int n = 0; n < 7; n++) { L[n] = lr[n] / denom; m = fmaxf(m, L[n]); }
            float s = 0.f;
            #pragma unroll
            for (int n = 0; n < 7; n++) { L[n] = expf(L[n] - m); s += L[n]; }
            #pragma unroll
            for (int n = 0; n < 7; n++) {
                float4 acc4 = {0.f, 0.f, 0.f, 0.f};
                #pragma unroll
                for (int oq = 0; oq < 16; oq++) {
                    float4 nb = nb4[rr][n*16 + oq];   // LDS broadcast (conflict-free)
                    acc4.x = fmaf(nb.x, wv4[oq].x, acc4.x);
                    acc4.y = fmaf(nb.y, wv4[oq].y, acc4.y);
                    acc4.z = fmaf(nb.z, wv4[oq].z, acc4.z);
                    acc4.w = fmaf(nb.w, wv4[oq].w, acc4.w);
                }
                float v = bv + ((acc4.x + acc4.y) + (acc4.z + acc4.w));
                va[n] = v >= 0.f ? v : 0.01f * v;
            }
            float acc = 0.f;
            #pragma unroll
            for (int n = 0; n < 7; n++) acc += (L[n] / s) * va[n];
            nb_all[((size_t)(a*4096 + b))*256 + h*128 + d] = acc;
        }
    }
}

// ---------------------------------------------------------------- k_stage2
// Tp[row,p] = sum_e nb_all[row,e]*G2[h,e,p]; lp[c] = dot(poi[c,b,:], Tp)/sqrt(D)
// Wave w holds G2[h, w*64+j, p] in 64 VGPRs (dup across halves). Lane=(sub,p):
// sub picks one of 2 rows per pair -> per-j loads hit 2 addresses, broadcast 32.
// block=256 (4 waves), 32 rows/block, grid = 16 ha * 128 tiles
__global__ __launch_bounds__(256, 2) void k_stage2(
        const float* __restrict__ obs, const float* __restrict__ nb_all,
        const float* __restrict__ G2, float* __restrict__ lp_raw,
        double* __restrict__ part2) {
    __shared__ float T_s[4][32][32];     // 16 KB
    __shared__ double dsum[4];
    int blk = blockIdx.x;
    int ha = blk >> 7, tile = blk & 127;
    int h = ha >> 3, a = ha & 7;
    int t = threadIdx.x, lane = t & 63;
    int sub = (lane >> 5), p = lane & 31;
    int wu = __builtin_amdgcn_readfirstlane(t >> 6);
    int rowb = a*4096 + tile*32;

    float Greg[64];
    const float* gbase = G2 + h*8192 + wu*64*32 + p;
    #pragma unroll
    for (int j = 0; j < 64; j++) Greg[j] = gbase[j*32];

    // phase 1: 16 row-pairs; lane's row = pair*2 + sub
    for (int rp = 0; rp < 16; rp++) {
        int r = rp*2 + sub;
        const float* nr = nb_all + (size_t)(rowb + r)*256 + wu*64;
        float acc = 0.f;
        #pragma unroll
        for (int q = 0; q < 16; q++) {
            float4 e4 = *(const float4*)(nr + 4*q);
            acc = fmaf(e4.x, Greg[4*q+0], acc);
            acc = fmaf(e4.y, Greg[4*q+1], acc);
            acc = fmaf(e4.z, Greg[4*q+2], acc);
            acc = fmaf(e4.w, Greg[4*q+3], acc);
        }
        T_s[wu][r][p] = acc;
    }
    __syncthreads();

    // phase 2: each wave finishes 8 rows; 2 c's per iteration (sub = c parity)
    double lsum = 0.0;
    for (int rr = 0; rr < 8; rr++) {
        int r = wu*8 + rr;
        int b = tile*32 + r;
        float Tp = (T_s[0][r][p] + T_s[1][r][p]) + (T_s[2][r][p] + T_s[3][r][p]);
        size_t pbase = (size_t)b*2560 + 512;   // poi lives in agent-0 rows
        for (int cb = 0; cb < 32; cb++) {
            int c = cb*2 + sub;
            float v = obs[pbase + cb*64 + lane] * Tp;   // coalesced 64 floats
            #pragma unroll
            for (int mm = 16; mm >= 1; mm >>= 1) v += __shfl_xor(v, mm, 32);
            v = v / SQRTD;
            if (p == 0) {
                lp_raw[(size_t)(ha*4096 + b)*64 + c] = v;
                lsum += (double)v;
            }
        }
    }
    // lanes 0 and 32 hold partial sums; combine then store per-wave
    lsum += __shfl_xor(lsum, 32, 64);
    if (lane == 0) dsum[wu] = lsum;
    __syncthreads();
    if (t == 0) part2[ha*128 + tile] = (dsum[0] + dsum[1]) + (dsum[2] + dsum[3]);
}

// ---------------------------------------------------------------- k_colmax_part
// per (ha, chunk of 256 b): softmax rows over c, track per-column (max w, min b)
// block=256 = 4 waves; lane c = t&63; grid = 16*16
__global__ void k_colmax_part(const float* __restrict__ lp_raw, const float* __restrict__ mean2,
                              float* __restrict__ colv_p, int* __restrict__ colb_p) {
    int blk = blockIdx.x;
    int ha = blk >> 4, chunk = blk & 15;
    int t = threadIdx.x, c = t & 63, wv = t >> 6;
    float denom = mean2[ha] + 1e-9f;
    float bestv = -1e30f; int bestb = 1 << 30;
    for (int k = 0; k < 64; k++) {
        int b = chunk*256 + wv + 4*k;
        float x = lp_raw[(size_t)(ha*4096 + b)*64 + c] / denom;
        float m = x;
        #pragma unroll
        for (int mm = 32; mm >= 1; mm >>= 1) m = fmaxf(m, __shfl_xor(m, mm, 64));
        float e = expf(x - m);
        float s = e;
        #pragma unroll
        for (int mm = 32; mm >= 1; mm >>= 1) s += __shfl_xor(s, mm, 64);
        float w = e / s;
        if (w > bestv) { bestv = w; bestb = b; }   // strict > keeps earliest b per thread
    }
    __shared__ float sv[4][64];
    __shared__ int   sb[4][64];
    sv[wv][c] = bestv; sb[wv][c] = bestb;
    __syncthreads();
    if (t < 64) {
        float v = sv[0][t]; int bb = sb[0][t];
        for (int j = 1; j < 4; j++) {
            float vj = sv[j][t]; int bj = sb[j][t];
            if (vj > v || (vj == v && bj < bb)) { v = vj; bb = bj; }
        }
        colv_p[(ha*16 + chunk)*64 + t] = v;
        colb_p[(ha*16 + chunk)*64 + t] = bb;
    }
}

// ---------------------------------------------------------------- k_colmerge
__global__ void k_colmerge(const float* __restrict__ colv_p, const int* __restrict__ colb_p,
                           float* __restrict__ colv, int* __restrict__ colb) {
    int ha = blockIdx.x, c = threadIdx.x;   // 64 threads
    float v = colv_p[(ha*16)*64 + c]; int bb = colb_p[(ha*16)*64 + c];
    for (int j = 1; j < 16; j++) {
        float vj = colv_p[(ha*16 + j)*64 + c]; int bj = colb_p[(ha*16 + j)*64 + c];
        if (vj > v || (vj == v && bj < bb)) { v = vj; bb = bj; }
    }
    colv[ha*64 + c] = v; colb[ha*64 + c] = bb;
}

// ---------------------------------------------------------------- k_scan
// 16-step sequential argmax scan, parallel over 64 lanes (one column each).
// Exact jnp.argmax first-occurrence semantics: masked column c contributes
// (0.0, flat=c); winner tie-break is (v desc, flat asc) via butterfly.
__global__ void k_scan(const float* __restrict__ obs, const float* __restrict__ colv,
                       const int* __restrict__ colb, float* __restrict__ out) {
    __shared__ float cif_s[8];
    int t = threadIdx.x;
    if (t < 64) {
        int c = t;
        int idx = (32*c + 2047) & 2047;          // (32c - 1) mod 2048
        float ifc = obs[512 + idx];              // agent 0, batch 0 cargo features
        float cv[16]; int cb[16];
        #pragma unroll
        for (int i = 0; i < 16; i++) { cv[i] = colv[i*64 + c]; cb[i] = colb[i*64 + c]; }
        float cif[8];
        for (int i = 0; i < 16; i++) {
            float v; int flat;
            if (ifc == 1.0f) { v = 0.0f; flat = c; }
            else { v = cv[i]; flat = cb[i]*64 + c; }
            #pragma unroll
            for (int mm = 32; mm >= 1; mm >>= 1) {
                float vo = __shfl_xor(v, mm, 64);
                int fo = __shfl_xor(flat, mm, 64);
                if (vo > v || (vo == v && fo < flat)) { v = vo; flat = fo; }
            }
            if (flat < 64 && c == flat) ifc = 1.0f;  // OOB scatter dropped, like JAX
            cif[i & 7] = (float)flat;                // agent = i % 8; later steps overwrite
        }
        if (t == 0) {
            #pragma unroll
            for (int a = 0; a < 8; a++) cif_s[a] = cif[a];
        }
    }
    __syncthreads();
    for (int a = 0; a < 8; a++)
        for (int k = t; k < 4096; k += 256)
            out[a*4096 + k] = cif_s[a];
}

// ---------------------------------------------------------------- launch
extern "C" void kernel_launch(void* const* d_in, const int* in_sizes, int n_in,
                              void* d_out, int out_size, void* d_ws, size_t ws_size,
                              hipStream_t stream) {
    const float* obs      = (const float*)d_in[0];
    const float* W_enc    = (const float*)d_in[1];
    const float* b_enc    = (const float*)d_in[2];
    const float* Wk_nb    = (const float*)d_in[3];
    const float* Wsel_nb  = (const float*)d_in[4];
    const float* Wv_nb    = (const float*)d_in[5];
    const float* bv_nb    = (const float*)d_in[6];
    const float* Wk_poi   = (const float*)d_in[7];
    const float* Wsel_poi = (const float*)d_in[8];
    // d_in[9] Wv_poi, d_in[10] bv_poi: unused by the reference output
    float* out = (float*)d_out;

    char* ws = (char*)d_ws;
    float*  enc       = (float*) (ws + 0);          // 33554432 B
    float*  nb_all    = (float*) (ws + 33554432);   // 33554432 B
    float*  lp_raw    = (float*) (ws + 67108864);   // 16777216 B
    float*  logit_raw = (float*) (ws + 83886080);   // 1835008 B
    float*  G         = (float*) (ws + 85721088);   // 131072 B
    float*  G2        = (float*) (ws + 85852160);   // 65536 B
    double* part1     = (double*)(ws + 85917696);   // 16384 B
    double* part2     = (double*)(ws + 85934080);   // 16384 B
    float*  mean1     = (float*) (ws + 85950464);   // 64 B
    float*  mean2     = (float*) (ws + 85950528);   // 64 B
    float*  colv_p    = (float*) (ws + 85950592);   // 65536 B
    int*    colb_p    = (int*)   (ws + 86016128);   // 65536 B
    float*  colv      = (float*) (ws + 86081664);   // 4096 B
    int*    colb      = (int*)   (ws + 86085760);   // 4096 B

    hipLaunchKernelGGL(k_G,           dim3(192),  dim3(256), 0, stream,
                       Wsel_nb, Wk_nb, Wsel_poi, Wk_poi, G, G2);
    hipLaunchKernelGGL(k_enc,         dim3(1024), dim3(128), 0, stream,
                       obs, W_enc, b_enc, enc);
    hipLaunchKernelGGL(k_stage1,      dim3(2048), dim3(256), 0, stream,
                       obs, enc, G, logit_raw, part1);
    hipLaunchKernelGGL(k_meanred,     dim3(16),   dim3(128), 0, stream,
                       part1, mean1, 28672);
    hipLaunchKernelGGL(k_nbvals,      dim3(1024), dim3(256), 0, stream,
                       obs, Wv_nb, bv_nb, logit_raw, mean1, nb_all);
    hipLaunchKernelGGL(k_stage2,      dim3(2048), dim3(256), 0, stream,
                       obs, nb_all, G2, lp_raw, part2);
    hipLaunchKernelGGL(k_meanred,     dim3(16),   dim3(128), 0, stream,
                       part2, mean2, 262144);
    hipLaunchKernelGGL(k_colmax_part, dim3(256),  dim3(256), 0, stream,
                       lp_raw, mean2, colv_p, colb_p);
    hipLaunchKernelGGL(k_colmerge,    dim3(16),   dim3(64),  0, stream,
                       colv_p, colb_p, colv, colb);
    hipLaunchKernelGGL(k_scan,        dim3(1),    dim3(256), 0, stream,
                       obs, colv, colb, out);
}